// Round 1
// baseline (12511.530 us; speedup 1.0000x reference)
//
#include <hip/hip_runtime.h>

#define B_SZ 32
#define S_LEN 2048
#define I_SZ 256
#define H_SZ 512
#define OUT_MAIN ((size_t)B_SZ * S_LEN * H_SZ)

typedef _Float16 half8 __attribute__((ext_vector_type(8)));
typedef _Float16 half4v __attribute__((ext_vector_type(4)));
typedef float floatx4 __attribute__((ext_vector_type(4)));

// ---------------------------------------------------------------------------
// Kernel 1: zero sync counters, convert W_ih / W_hh / h0 to f16 in workspace.
// ---------------------------------------------------------------------------
__global__ void rnn_init(const float* __restrict__ wih, const float* __restrict__ whh,
                         const float* __restrict__ h0,
                         _Float16* __restrict__ wih16, _Float16* __restrict__ whh16,
                         _Float16* __restrict__ h16, unsigned* __restrict__ cnt) {
  int idx = blockIdx.x * blockDim.x + threadIdx.x;
  int stride = gridDim.x * blockDim.x;
  if (idx < 8) cnt[idx] = 0;  // ws is poisoned 0xAA every call; must re-zero
  for (int i = idx; i < H_SZ * I_SZ; i += stride) wih16[i] = (_Float16)wih[i];
  for (int i = idx; i < H_SZ * H_SZ; i += stride) whh16[i] = (_Float16)whh[i];
  // h0 -> slot 0 of the double buffer (step t reads slot t&1)
  for (int i = idx; i < B_SZ * H_SZ; i += stride) h16[i] = (_Float16)h0[i];
}

// ---------------------------------------------------------------------------
// Kernel 2: z' = inputs @ W_ih^T + b_ih + b_hh, written straight into d_out
// in [B,S,H] layout (GEMM M-index = b*S+t IS d_out's natural order).
// f16 MFMA 16x16x32; A (inputs) converted fp32->f16 in-register, B from ws.
// Wave = one 16-row m-tile x all 32 n-tiles (acc = 128 VGPRs).
// ---------------------------------------------------------------------------
__launch_bounds__(256, 2)
__global__ void rnn_zin(const float* __restrict__ inputs, const _Float16* __restrict__ wih16,
                        const float* __restrict__ bih, const float* __restrict__ bhh,
                        float* __restrict__ out) {
  const int wave = threadIdx.x >> 6;
  const int lane = threadIdx.x & 63;
  const int col = lane & 15;   // A: m-lane / D: n-col
  const int quad = lane >> 4;  // k = quad*8 + i for A/B frags
  const int m0 = blockIdx.x * 64 + wave * 16;

  floatx4 acc[32];
#pragma unroll
  for (int nt = 0; nt < 32; ++nt) acc[nt] = (floatx4){0.f, 0.f, 0.f, 0.f};

#pragma unroll
  for (int kt = 0; kt < 8; ++kt) {
    const float* ap = inputs + (size_t)(m0 + col) * I_SZ + kt * 32 + quad * 8;
    float4 a0 = *(const float4*)(ap);
    float4 a1 = *(const float4*)(ap + 4);
    half8 af;
    af[0] = (_Float16)a0.x; af[1] = (_Float16)a0.y; af[2] = (_Float16)a0.z; af[3] = (_Float16)a0.w;
    af[4] = (_Float16)a1.x; af[5] = (_Float16)a1.y; af[6] = (_Float16)a1.z; af[7] = (_Float16)a1.w;
#pragma unroll
    for (int nt = 0; nt < 32; ++nt) {
      half8 bf = *(const half8*)(wih16 + (size_t)(nt * 16 + col) * I_SZ + kt * 32 + quad * 8);
      acc[nt] = __builtin_amdgcn_mfma_f32_16x16x32_f16(af, bf, acc[nt], 0, 0, 0);
    }
  }

  // C/D layout: col = lane&15 (=n=j), row = quad*4 + r (=m)
#pragma unroll
  for (int nt = 0; nt < 32; ++nt) {
    const int j = nt * 16 + col;
    const float bias = bih[j] + bhh[j];
#pragma unroll
    for (int r = 0; r < 4; ++r) {
      const int m = m0 + quad * 4 + r;
      out[(size_t)m * H_SZ + j] = acc[nt][r] + bias;
    }
  }
}

// ---------------------------------------------------------------------------
// Kernel 3: persistent recurrence. 8 blocks x 256 threads (co-resident on 8
// CUs -> no deadlock). blockIdx = gb*4 + slice: slice owns j in
// [slice*128, +128), gb owns batches [gb*16, +16). Thread pins its W_hh
// slice as 32 f16 A-fragments (128 VGPRs) -> no W traffic per step.
// Sync: per-group monotonic counter in ws, agent-scope release/acquire.
// h exchanged via f16 double buffer in ws; z consumed in place from d_out.
// ---------------------------------------------------------------------------
__launch_bounds__(256, 1)
__global__ void rnn_steps(const _Float16* __restrict__ whh16, float* __restrict__ out,
                          _Float16* __restrict__ h16, unsigned* __restrict__ cnt) {
  const int wave = threadIdx.x >> 6;
  const int lane = threadIdx.x & 63;
  const int col = lane & 15;
  const int quad = lane >> 4;
  const int slice = blockIdx.x & 3;
  const int gb = blockIdx.x >> 2;
  const int j0 = slice * 128;
  const int b = gb * 16 + col;  // batch for B-frag (n) and epilogue col
  unsigned* cg = cnt + gb;

  // Pin W_hh A-fragments: wave covers m-tiles {wave*2, wave*2+1} of the slice.
  half8 wA[2][16];
#pragma unroll
  for (int mm = 0; mm < 2; ++mm) {
    const int m = j0 + (wave * 2 + mm) * 16 + col;
#pragma unroll
    for (int kt = 0; kt < 16; ++kt)
      wA[mm][kt] = *(const half8*)(whh16 + (size_t)m * H_SZ + kt * 32 + quad * 8);
  }

  for (int t = 0; t < S_LEN; ++t) {
    // Prefetch this step's z (not peer-dependent) before the sync wait.
    float4 zf[2];
#pragma unroll
    for (int mm = 0; mm < 2; ++mm) {
      const int j = j0 + (wave * 2 + mm) * 16 + quad * 4;
      zf[mm] = *(const float4*)(out + ((size_t)b * S_LEN + t) * H_SZ + j);
    }

    if (t > 0) {
      if (threadIdx.x == 0) {
        const unsigned tgt = 4u * (unsigned)t;
        while (__hip_atomic_load(cg, __ATOMIC_ACQUIRE, __HIP_MEMORY_SCOPE_AGENT) < tgt) {}
      }
      __syncthreads();
    }

    const _Float16* hin = h16 + (size_t)(t & 1) * (B_SZ * H_SZ);
    half8 bF[16];
#pragma unroll
    for (int kt = 0; kt < 16; ++kt)
      bF[kt] = *(const half8*)(hin + (size_t)b * H_SZ + kt * 32 + quad * 8);

    floatx4 acc0 = (floatx4){0.f, 0.f, 0.f, 0.f};
    floatx4 acc1 = (floatx4){0.f, 0.f, 0.f, 0.f};
#pragma unroll
    for (int kt = 0; kt < 16; ++kt) {
      acc0 = __builtin_amdgcn_mfma_f32_16x16x32_f16(wA[0][kt], bF[kt], acc0, 0, 0, 0);
      acc1 = __builtin_amdgcn_mfma_f32_16x16x32_f16(wA[1][kt], bF[kt], acc1, 0, 0, 0);
    }

    _Float16* hout = h16 + (size_t)((t + 1) & 1) * (B_SZ * H_SZ);
#pragma unroll
    for (int mm = 0; mm < 2; ++mm) {
      const floatx4 a = (mm == 0) ? acc0 : acc1;
      const int j = j0 + (wave * 2 + mm) * 16 + quad * 4;
      const size_t zi = ((size_t)b * S_LEN + t) * H_SZ + j;
      const float h0v = fmaxf(zf[mm].x + a[0], 0.f);
      const float h1v = fmaxf(zf[mm].y + a[1], 0.f);
      const float h2v = fmaxf(zf[mm].z + a[2], 0.f);
      const float h3v = fmaxf(zf[mm].w + a[3], 0.f);
      *(float4*)(out + zi) = make_float4(h0v, h1v, h2v, h3v);  // in-place z -> h
      half4v hh;
      hh[0] = (_Float16)h0v; hh[1] = (_Float16)h1v; hh[2] = (_Float16)h2v; hh[3] = (_Float16)h3v;
      *(half4v*)(hout + (size_t)b * H_SZ + j) = hh;
      if (t == S_LEN - 1)  // h_final tail of d_out
        *(float4*)(out + OUT_MAIN + (size_t)b * H_SZ + j) = make_float4(h0v, h1v, h2v, h3v);
    }

    __threadfence();  // agent-scope: flush h16/out stores toward coherence point
    __syncthreads();
    if (threadIdx.x == 0)
      __hip_atomic_fetch_add(cg, 1u, __ATOMIC_RELEASE, __HIP_MEMORY_SCOPE_AGENT);
  }
}

extern "C" void kernel_launch(void* const* d_in, const int* in_sizes, int n_in,
                              void* d_out, int out_size, void* d_ws, size_t ws_size,
                              hipStream_t stream) {
  (void)in_sizes; (void)n_in; (void)out_size; (void)ws_size;
  const float* inputs = (const float*)d_in[0];
  const float* h0     = (const float*)d_in[1];
  const float* wih    = (const float*)d_in[2];
  const float* whh    = (const float*)d_in[3];
  const float* bih    = (const float*)d_in[4];
  const float* bhh    = (const float*)d_in[5];
  float* out = (float*)d_out;

  char* ws = (char*)d_ws;
  unsigned* cnt   = (unsigned*)(ws);                          // 8 counters (use 2)
  _Float16* wih16 = (_Float16*)(ws + 512);                    // 512*256 f16 = 256 KB
  _Float16* whh16 = (_Float16*)(ws + 512 + 262144);           // 512*512 f16 = 512 KB
  _Float16* h16   = (_Float16*)(ws + 512 + 262144 + 524288);  // 2*32*512 f16 = 64 KB

  rnn_init<<<64, 256, 0, stream>>>(wih, whh, h0, wih16, whh16, h16, cnt);
  rnn_zin<<<1024, 256, 0, stream>>>(inputs, wih16, bih, bhh, out);
  rnn_steps<<<8, 256, 0, stream>>>(whh16, out, h16, cnt);
}

// Round 2
// 11748.849 us; speedup vs baseline: 1.0649x; 1.0649x over previous
//
#include <hip/hip_runtime.h>

#define B_SZ 32
#define S_LEN 2048
#define I_SZ 256
#define H_SZ 512
#define OUT_MAIN ((size_t)B_SZ * S_LEN * H_SZ)

typedef _Float16 half8 __attribute__((ext_vector_type(8)));
typedef _Float16 half4v __attribute__((ext_vector_type(4)));
typedef float floatx4 __attribute__((ext_vector_type(4)));
typedef unsigned long long u64;

// ---------------------------------------------------------------------------
// Kernel 1: zero per-block flags, convert W_ih / W_hh / h0 to f16 in ws.
// Plain stores are fine: the implicit end-of-kernel release (L2 writeback)
// makes them visible to rnn_steps' cache-bypassing atomic loads.
// ---------------------------------------------------------------------------
__global__ void rnn_init(const float* __restrict__ wih, const float* __restrict__ whh,
                         const float* __restrict__ h0,
                         _Float16* __restrict__ wih16, _Float16* __restrict__ whh16,
                         _Float16* __restrict__ h16, unsigned* __restrict__ flags) {
  int idx = blockIdx.x * blockDim.x + threadIdx.x;
  int stride = gridDim.x * blockDim.x;
  if (idx < 128) flags[idx] = 0;  // ws is poisoned 0xAA every call; must re-zero
  for (int i = idx; i < H_SZ * I_SZ; i += stride) wih16[i] = (_Float16)wih[i];
  for (int i = idx; i < H_SZ * H_SZ; i += stride) whh16[i] = (_Float16)whh[i];
  // h0 -> slot 0 of the double buffer (step t reads slot t&1)
  for (int i = idx; i < B_SZ * H_SZ; i += stride) h16[i] = (_Float16)h0[i];
}

// ---------------------------------------------------------------------------
// Kernel 2: z' = inputs @ W_ih^T + b_ih + b_hh -> d_out in [B,S,H] layout.
// (unchanged from round 1 — minor cost; isolate the sync fix this round)
// ---------------------------------------------------------------------------
__launch_bounds__(256, 2)
__global__ void rnn_zin(const float* __restrict__ inputs, const _Float16* __restrict__ wih16,
                        const float* __restrict__ bih, const float* __restrict__ bhh,
                        float* __restrict__ out) {
  const int wave = threadIdx.x >> 6;
  const int lane = threadIdx.x & 63;
  const int col = lane & 15;
  const int quad = lane >> 4;
  const int m0 = blockIdx.x * 64 + wave * 16;

  floatx4 acc[32];
#pragma unroll
  for (int nt = 0; nt < 32; ++nt) acc[nt] = (floatx4){0.f, 0.f, 0.f, 0.f};

#pragma unroll
  for (int kt = 0; kt < 8; ++kt) {
    const float* ap = inputs + (size_t)(m0 + col) * I_SZ + kt * 32 + quad * 8;
    float4 a0 = *(const float4*)(ap);
    float4 a1 = *(const float4*)(ap + 4);
    half8 af;
    af[0] = (_Float16)a0.x; af[1] = (_Float16)a0.y; af[2] = (_Float16)a0.z; af[3] = (_Float16)a0.w;
    af[4] = (_Float16)a1.x; af[5] = (_Float16)a1.y; af[6] = (_Float16)a1.z; af[7] = (_Float16)a1.w;
#pragma unroll
    for (int nt = 0; nt < 32; ++nt) {
      half8 bf = *(const half8*)(wih16 + (size_t)(nt * 16 + col) * I_SZ + kt * 32 + quad * 8);
      acc[nt] = __builtin_amdgcn_mfma_f32_16x16x32_f16(af, bf, acc[nt], 0, 0, 0);
    }
  }

#pragma unroll
  for (int nt = 0; nt < 32; ++nt) {
    const int j = nt * 16 + col;
    const float bias = bih[j] + bhh[j];
#pragma unroll
    for (int r = 0; r < 4; ++r) {
      const int m = m0 + quad * 4 + r;
      out[(size_t)m * H_SZ + j] = acc[nt][r] + bias;
    }
  }
}

// ---------------------------------------------------------------------------
// Kernel 3: persistent recurrence, fence-free sync.
// 8 blocks: blockIdx = gb*4 + slice. slice owns j in [slice*128,+128),
// group gb owns batches [gb*16,+16). W_hh slice pinned in VGPRs (128/thread).
// Cross-block exchange: h as RELAXED agent-scope u64 atomics (cache-bypass,
// served at MALL — NO buffer_wbl2/buffer_inv). Data->flag ordering: explicit
// s_waitcnt + __syncthreads (per-wave vmcnt drain) before thread0's relaxed
// flag store. Readers poll 3 peer flags with relaxed loads, no barrier.
// ---------------------------------------------------------------------------
__launch_bounds__(256, 1)
__global__ void rnn_steps(const _Float16* __restrict__ whh16, float* __restrict__ out,
                          u64* __restrict__ h16, unsigned* __restrict__ flags) {
  const int wave = threadIdx.x >> 6;
  const int lane = threadIdx.x & 63;
  const int col = lane & 15;
  const int quad = lane >> 4;
  const int slice = blockIdx.x & 3;
  const int gb = blockIdx.x >> 2;
  const int j0 = slice * 128;
  const int b = gb * 16 + col;

  // Peer flags (same group, other slices). Stride 16 u32 = 64 B apart.
  unsigned* fs = flags + (size_t)(gb * 4 + slice) * 16;
  unsigned* f0 = flags + (size_t)(gb * 4 + ((slice + 1) & 3)) * 16;
  unsigned* f1 = flags + (size_t)(gb * 4 + ((slice + 2) & 3)) * 16;
  unsigned* f2 = flags + (size_t)(gb * 4 + ((slice + 3) & 3)) * 16;

  // Pin W_hh A-fragments: wave covers m-tiles {wave*2, wave*2+1} of the slice.
  half8 wA[2][16];
#pragma unroll
  for (int mm = 0; mm < 2; ++mm) {
    const int m = j0 + (wave * 2 + mm) * 16 + col;
#pragma unroll
    for (int kt = 0; kt < 16; ++kt)
      wA[mm][kt] = *(const half8*)(whh16 + (size_t)m * H_SZ + kt * 32 + quad * 8);
  }

  for (int t = 0; t < S_LEN; ++t) {
    // Prefetch this step's z (own data, not peer-dependent) before the wait.
    float4 zf[2];
#pragma unroll
    for (int mm = 0; mm < 2; ++mm) {
      const int j = j0 + (wave * 2 + mm) * 16 + quad * 4;
      zf[mm] = *(const float4*)(out + ((size_t)b * S_LEN + t) * H_SZ + j);
    }

    if (t > 0) {
      const unsigned tgt = (unsigned)t;
      while (__hip_atomic_load(f0, __ATOMIC_RELAXED, __HIP_MEMORY_SCOPE_AGENT) < tgt ||
             __hip_atomic_load(f1, __ATOMIC_RELAXED, __HIP_MEMORY_SCOPE_AGENT) < tgt ||
             __hip_atomic_load(f2, __ATOMIC_RELAXED, __HIP_MEMORY_SCOPE_AGENT) < tgt) {}
      asm volatile("" ::: "memory");  // don't hoist data loads above the poll
    }

    // Load peer h (slot t&1) via cache-bypass atomics: fresh at the MALL.
    const u64* hin = h16 + (size_t)(t & 1) * (B_SZ * H_SZ / 4) + (size_t)b * (H_SZ / 4);
    half8 bF[16];
#pragma unroll
    for (int kt = 0; kt < 16; ++kt) {
      u64 lo = __hip_atomic_load(hin + kt * 8 + quad * 2, __ATOMIC_RELAXED, __HIP_MEMORY_SCOPE_AGENT);
      u64 hi = __hip_atomic_load(hin + kt * 8 + quad * 2 + 1, __ATOMIC_RELAXED, __HIP_MEMORY_SCOPE_AGENT);
      union { u64 q[2]; half8 h; } cv;
      cv.q[0] = lo; cv.q[1] = hi;
      bF[kt] = cv.h;
    }

    floatx4 acc0 = (floatx4){0.f, 0.f, 0.f, 0.f};
    floatx4 acc1 = (floatx4){0.f, 0.f, 0.f, 0.f};
#pragma unroll
    for (int kt = 0; kt < 16; ++kt) {
      acc0 = __builtin_amdgcn_mfma_f32_16x16x32_f16(wA[0][kt], bF[kt], acc0, 0, 0, 0);
      acc1 = __builtin_amdgcn_mfma_f32_16x16x32_f16(wA[1][kt], bF[kt], acc1, 0, 0, 0);
    }

    u64* hout = h16 + (size_t)((t + 1) & 1) * (B_SZ * H_SZ / 4) + (size_t)b * (H_SZ / 4);
#pragma unroll
    for (int mm = 0; mm < 2; ++mm) {
      const floatx4 a = (mm == 0) ? acc0 : acc1;
      const int j = j0 + (wave * 2 + mm) * 16 + quad * 4;
      const size_t zi = ((size_t)b * S_LEN + t) * H_SZ + j;
      const float h0v = fmaxf(zf[mm].x + a[0], 0.f);
      const float h1v = fmaxf(zf[mm].y + a[1], 0.f);
      const float h2v = fmaxf(zf[mm].z + a[2], 0.f);
      const float h3v = fmaxf(zf[mm].w + a[3], 0.f);
      *(float4*)(out + zi) = make_float4(h0v, h1v, h2v, h3v);  // in-place z -> h
      union { half4v h; u64 q; } pk;
      pk.h[0] = (_Float16)h0v; pk.h[1] = (_Float16)h1v;
      pk.h[2] = (_Float16)h2v; pk.h[3] = (_Float16)h3v;
      __hip_atomic_store(hout + j / 4, pk.q, __ATOMIC_RELAXED, __HIP_MEMORY_SCOPE_AGENT);
      if (t == S_LEN - 1)  // h_final tail of d_out
        *(float4*)(out + OUT_MAIN + (size_t)b * H_SZ + j) = make_float4(h0v, h1v, h2v, h3v);
    }

    // Drain this wave's stores, barrier all waves, then publish the flag.
    asm volatile("s_waitcnt vmcnt(0)" ::: "memory");
    __syncthreads();
    if (threadIdx.x == 0)
      __hip_atomic_store(fs, (unsigned)(t + 1), __ATOMIC_RELAXED, __HIP_MEMORY_SCOPE_AGENT);
  }
}

extern "C" void kernel_launch(void* const* d_in, const int* in_sizes, int n_in,
                              void* d_out, int out_size, void* d_ws, size_t ws_size,
                              hipStream_t stream) {
  (void)in_sizes; (void)n_in; (void)out_size; (void)ws_size;
  const float* inputs = (const float*)d_in[0];
  const float* h0     = (const float*)d_in[1];
  const float* wih    = (const float*)d_in[2];
  const float* whh    = (const float*)d_in[3];
  const float* bih    = (const float*)d_in[4];
  const float* bhh    = (const float*)d_in[5];
  float* out = (float*)d_out;

  char* ws = (char*)d_ws;
  unsigned* flags  = (unsigned*)(ws);                          // 128 u32 = 512 B
  _Float16* wih16 = (_Float16*)(ws + 512);                     // 256 KB
  _Float16* whh16 = (_Float16*)(ws + 512 + 262144);            // 512 KB
  _Float16* h16   = (_Float16*)(ws + 512 + 262144 + 524288);   // 64 KB

  rnn_init<<<64, 256, 0, stream>>>(wih, whh, h0, wih16, whh16, h16, flags);
  rnn_zin<<<1024, 256, 0, stream>>>(inputs, wih16, bih, bhh, out);
  rnn_steps<<<8, 256, 0, stream>>>(whh16, out, (u64*)h16, flags);
}